// Round 10
// baseline (2167.759 us; speedup 1.0000x reference)
//
#include <hip/hip_runtime.h>
#include <stdint.h>

#define DD 128
#define LDSROW 136  // 128 cols + 8 pad (ushort)

typedef __attribute__((ext_vector_type(8))) short short8;
typedef __attribute__((ext_vector_type(4))) float float4v;

// ---------- bf16 helpers (RTNE) ----------
__device__ __forceinline__ unsigned short f2bf(float f) {
  unsigned u = __float_as_uint(f);
  unsigned r = u + 0x7fffu + ((u >> 16) & 1u);
  return (unsigned short)(r >> 16);
}
__device__ __forceinline__ unsigned pack2(float a, float b) {
  return (unsigned)f2bf(a) | ((unsigned)f2bf(b) << 16);
}
__device__ __forceinline__ float2 unpack2(unsigned p) {
  float2 r;
  r.x = __uint_as_float(p << 16);
  r.y = __uint_as_float(p & 0xffff0000u);
  return r;
}

// ---------- dispatch 2: degree histogram + weight frag prep (role-split grid) ----------
__global__ __launch_bounds__(256) void k_deg_prep(const int* __restrict__ dst, int* deg, int e, int eb,
                                                  const float* __restrict__ W1, const float* __restrict__ W2,
                                                  const float* __restrict__ Wself, const float* __restrict__ Wneigh,
                                                  unsigned* __restrict__ wfrag) {
  int b = blockIdx.x;
  if (b < eb) {
    int i = b * 256 + threadIdx.x;
    if (i < e) atomicAdd(&deg[dst[i]], 1);
  } else {
    int gid = (b - eb) * 256 + threadIdx.x;  // 0 .. 65535
    int m = gid >> 13;
    int r = gid & 8191;
    int p = r & 3;
    int lane = (r >> 2) & 63;
    int t = (r >> 8) & 3;
    int c = r >> 10;
    const float* W;
    if (m == 0) W = W1;
    else if (m == 1) W = W2;
    else if (m < 5) W = Wself + (size_t)(m - 2) * DD * DD;
    else W = Wneigh + (size_t)(m - 5) * DD * DD;
    int n = c * 16 + (lane & 15);
    int k = t * 32 + (lane >> 4) * 8 + 2 * p;
    wfrag[gid] = pack2(W[(size_t)k * DD + n], W[(size_t)(k + 1) * DD + n]);
  }
}

// ---------- dispatch 3: segment allocator (replaces both scans) ----------
// Per-wave shuffle-scan of 64 degrees + ONE atomicAdd per wave on a global counter.
// CSR segments land in arbitrary order — harmless: aggr uses deg[] for counts.
__global__ __launch_bounds__(256) void k_alloc(const int* __restrict__ deg, int* total,
                                               int* __restrict__ rowstart, int* __restrict__ cursor, int n) {
  int i = blockIdx.x * 256 + threadIdx.x;
  int lane = threadIdx.x & 63;
  int d = (i < n) ? deg[i] : 0;
  int v = d;
#pragma unroll
  for (int off = 1; off < 64; off <<= 1) {
    int u = __shfl_up(v, off);
    if (lane >= off) v += u;
  }
  int wtot = __shfl(v, 63);
  int base = 0;
  if (lane == 63) base = atomicAdd(total, wtot);
  base = __shfl(base, 63);
  if (i < n) {
    int excl = base + v - d;
    rowstart[i] = excl;
    cursor[i] = excl;
  }
}

// ---------- dispatch 4: range-partitioned fill | fused fc_in (role-split grid) ----------
__global__ __launch_bounds__(256) void k_fill_fc(const int* __restrict__ src, const int* __restrict__ dst,
                                                 int* cursor, int* __restrict__ esrc, int e, int rstep, int fb,
                                                 const float* __restrict__ hin,
                                                 const uint4* __restrict__ wf1, const uint4* __restrict__ wf2,
                                                 const float* __restrict__ b1, const float* __restrict__ b2,
                                                 unsigned short* __restrict__ actB, int n) {
  __shared__ unsigned short sT[64 * LDSROW];
  int b = blockIdx.x;
  if (b < fb) {
    // fill role: range = b&7, L2-local write windows
    int range = b & 7;
    int i = (b >> 3) * 256 + threadIdx.x;
    if (i >= e) return;
    int d = dst[i];
    int lo = range * rstep;
    if (d >= lo && d < lo + rstep) {
      int p = atomicAdd(&cursor[d], 1);
      esrc[p] = src[i];
    }
  } else {
    // fc12 role
    int tile = b - fb;
    int tid = threadIdx.x, w = tid >> 6, lane = tid & 63;
    int q = lane >> 4, nn = lane & 15;
    int r0 = tile * 64 + w * 16;
    int rr = r0 + nn; if (rr >= n) rr = n - 1;
    short8 a[4];
    {
      const float* X = hin + (size_t)rr * DD;
#pragma unroll
      for (int t = 0; t < 4; ++t) {
        int k0 = t * 32 + q * 8;
        float4 f0 = *(const float4*)&X[k0];
        float4 f1 = *(const float4*)&X[k0 + 4];
        uint4 u;
        u.x = pack2(f0.x, f0.y); u.y = pack2(f0.z, f0.w);
        u.z = pack2(f1.x, f1.y); u.w = pack2(f1.z, f1.w);
        a[t] = __builtin_bit_cast(short8, u);
      }
    }
    float4v acc[8];
#pragma unroll
    for (int c = 0; c < 8; ++c) acc[c] = (float4v){0.f, 0.f, 0.f, 0.f};
#pragma unroll
    for (int c = 0; c < 8; ++c) {
#pragma unroll
      for (int t = 0; t < 4; ++t) {
        short8 bb = __builtin_bit_cast(short8, wf1[(c * 4 + t) * 64 + lane]);
        acc[c] = __builtin_amdgcn_mfma_f32_16x16x32_bf16(a[t], bb, acc[c], 0, 0, 0);
      }
    }
#pragma unroll
    for (int c = 0; c < 8; ++c) {
      float bc = b1[c * 16 + nn];
#pragma unroll
      for (int g = 0; g < 4; ++g) {
        int lr = w * 16 + q * 4 + g;
        sT[lr * LDSROW + c * 16 + nn] = f2bf(tanhf(acc[c][g] + bc));
      }
    }
    __syncthreads();
    short8 a2[4];
#pragma unroll
    for (int t = 0; t < 4; ++t) {
      const uint4* p = (const uint4*)&sT[(w * 16 + nn) * LDSROW + (t * 4 + q) * 8];
      a2[t] = __builtin_bit_cast(short8, *p);
    }
    float4v acc2[8];
#pragma unroll
    for (int c = 0; c < 8; ++c) acc2[c] = (float4v){0.f, 0.f, 0.f, 0.f};
#pragma unroll
    for (int c = 0; c < 8; ++c) {
#pragma unroll
      for (int t = 0; t < 4; ++t) {
        short8 bb = __builtin_bit_cast(short8, wf2[(c * 4 + t) * 64 + lane]);
        acc2[c] = __builtin_amdgcn_mfma_f32_16x16x32_bf16(a2[t], bb, acc2[c], 0, 0, 0);
      }
    }
#pragma unroll
    for (int c = 0; c < 8; ++c) {
      float bc = b2[c * 16 + nn];
#pragma unroll
      for (int g = 0; g < 4; ++g) {
        int row = r0 + q * 4 + g;
        if (row < n) actB[(size_t)row * DD + c * 16 + nn] = f2bf(acc2[c][g] + bc);
      }
    }
  }
}

// ---------- dispatches 5-7: one per layer. aggr blocks (full TLP, never wait) + ----------
// ---------- sage blocks gated per-64-row-tile by release/acquire flag counters ----------
// ACT: 1 tanh, 2 silu
template <int ACT, bool OUTF32>
__global__ __launch_bounds__(256) void k_layer_pc(const uint4* __restrict__ X,
                                                  const int* __restrict__ rowstart, const int* __restrict__ degc,
                                                  const int* __restrict__ esrc, uint4* __restrict__ neigh,
                                                  int* flags,
                                                  const uint4* __restrict__ wfs, const uint4* __restrict__ wfn,
                                                  const float* __restrict__ bias, void* __restrict__ outp,
                                                  int n, int ab) {
  int b = blockIdx.x;
  if (b < ab) {
    // ---- aggr role: 4 rows, one per wave; 16 gathers in flight per wave ----
    int wave = threadIdx.x >> 6, lane = threadIdx.x & 63;
    int g = lane >> 4, nn = lane & 15;
    int r = b * 4 + wave;
    if (r < n) {
      int ru = __builtin_amdgcn_readfirstlane(r);
      int beg = rowstart[ru];
      int cnt = degc[ru];
      float acc[8];
#pragma unroll
      for (int i = 0; i < 8; ++i) acc[i] = 0.f;
      int base = 0;
      for (; base + 16 <= cnt; base += 16) {
        int j0 = beg + base + g;
        int s0 = esrc[j0];
        int s1 = esrc[j0 + 4];
        int s2 = esrc[j0 + 8];
        int s3 = esrc[j0 + 12];
        uint4 v0 = X[(size_t)s0 * 16 + nn];
        uint4 v1 = X[(size_t)s1 * 16 + nn];
        uint4 v2 = X[(size_t)s2 * 16 + nn];
        uint4 v3 = X[(size_t)s3 * 16 + nn];
        const unsigned* u0 = (const unsigned*)&v0;
        const unsigned* u1 = (const unsigned*)&v1;
        const unsigned* u2 = (const unsigned*)&v2;
        const unsigned* u3 = (const unsigned*)&v3;
#pragma unroll
        for (int k = 0; k < 4; ++k) {
          float2 f0 = unpack2(u0[k]), f1 = unpack2(u1[k]);
          float2 f2 = unpack2(u2[k]), f3 = unpack2(u3[k]);
          acc[2 * k]     += (f0.x + f1.x) + (f2.x + f3.x);
          acc[2 * k + 1] += (f0.y + f1.y) + (f2.y + f3.y);
        }
      }
      for (; base + 8 <= cnt; base += 8) {
        int j0 = beg + base + g;
        int s0 = esrc[j0];
        int s1 = esrc[j0 + 4];
        uint4 v0 = X[(size_t)s0 * 16 + nn];
        uint4 v1 = X[(size_t)s1 * 16 + nn];
        const unsigned* u0 = (const unsigned*)&v0;
        const unsigned* u1 = (const unsigned*)&v1;
#pragma unroll
        for (int k = 0; k < 4; ++k) {
          float2 f0 = unpack2(u0[k]), f1 = unpack2(u1[k]);
          acc[2 * k] += f0.x + f1.x;
          acc[2 * k + 1] += f0.y + f1.y;
        }
      }
      if (base + g < cnt) {
        int s = esrc[beg + base + g];
        uint4 v = X[(size_t)s * 16 + nn];
        const unsigned* u = (const unsigned*)&v;
#pragma unroll
        for (int k = 0; k < 4; ++k) {
          float2 f = unpack2(u[k]);
          acc[2 * k] += f.x;
          acc[2 * k + 1] += f.y;
        }
      }
      if (base + 4 + g < cnt) {
        int s = esrc[beg + base + 4 + g];
        uint4 v = X[(size_t)s * 16 + nn];
        const unsigned* u = (const unsigned*)&v;
#pragma unroll
        for (int k = 0; k < 4; ++k) {
          float2 f = unpack2(u[k]);
          acc[2 * k] += f.x;
          acc[2 * k + 1] += f.y;
        }
      }
#pragma unroll
      for (int k = 0; k < 8; ++k) {
        acc[k] += __shfl_xor(acc[k], 16, 64);
        acc[k] += __shfl_xor(acc[k], 32, 64);
      }
      if (g == 0) {
        float inv = 1.0f / (float)(cnt > 1 ? cnt : 1);
        uint4 o;
        o.x = pack2(acc[0] * inv, acc[1] * inv);
        o.y = pack2(acc[2] * inv, acc[3] * inv);
        o.z = pack2(acc[4] * inv, acc[5] * inv);
        o.w = pack2(acc[6] * inv, acc[7] * inv);
        neigh[(size_t)r * 16 + nn] = o;
      }
    }
    __syncthreads();
    if (threadIdx.x == 0) {
      __threadfence();  // release neigh writes
      __hip_atomic_fetch_add(&flags[b >> 4], 1, __ATOMIC_RELEASE, __HIP_MEMORY_SCOPE_AGENT);
    }
  } else {
    // ---- sage role: wait for this tile's 16 (or fewer) aggr blocks, then GEMM ----
    int t = b - ab;  // tile index, 64 rows
    int expect = ab - t * 16; if (expect > 16) expect = 16;
    if (threadIdx.x == 0) {
      int v = __hip_atomic_load(&flags[t], __ATOMIC_ACQUIRE, __HIP_MEMORY_SCOPE_AGENT);
      while (v < expect) {
        __builtin_amdgcn_s_sleep(8);
        v = __hip_atomic_load(&flags[t], __ATOMIC_ACQUIRE, __HIP_MEMORY_SCOPE_AGENT);
      }
      __threadfence();  // acquire: invalidate stale L1
    }
    __syncthreads();
    int tid = threadIdx.x, w = tid >> 6, lane = tid & 63;
    int q = lane >> 4, nn = lane & 15;
    int r0 = t * 64 + w * 16;
    int rr = r0 + nn; if (rr >= n) rr = n - 1;
    short8 a[4], g[4];
    {
      const uint4* Xr = X + (size_t)rr * 16;
      const uint4* Gr = neigh + (size_t)rr * 16;
#pragma unroll
      for (int tt = 0; tt < 4; ++tt) {
        a[tt] = __builtin_bit_cast(short8, Xr[tt * 4 + q]);
        g[tt] = __builtin_bit_cast(short8, Gr[tt * 4 + q]);
      }
    }
    float4v acc[8];
#pragma unroll
    for (int c = 0; c < 8; ++c) acc[c] = (float4v){0.f, 0.f, 0.f, 0.f};
#pragma unroll
    for (int c = 0; c < 8; ++c) {
#pragma unroll
      for (int tt = 0; tt < 4; ++tt) {
        short8 bb = __builtin_bit_cast(short8, wfs[(c * 4 + tt) * 64 + lane]);
        acc[c] = __builtin_amdgcn_mfma_f32_16x16x32_bf16(a[tt], bb, acc[c], 0, 0, 0);
      }
#pragma unroll
      for (int tt = 0; tt < 4; ++tt) {
        short8 bb = __builtin_bit_cast(short8, wfn[(c * 4 + tt) * 64 + lane]);
        acc[c] = __builtin_amdgcn_mfma_f32_16x16x32_bf16(g[tt], bb, acc[c], 0, 0, 0);
      }
    }
#pragma unroll
    for (int c = 0; c < 8; ++c) {
      float bc = bias[c * 16 + nn];
#pragma unroll
      for (int gg = 0; gg < 4; ++gg) {
        int row = r0 + q * 4 + gg;
        if (row < n) {
          float v = acc[c][gg] + bc;
          if (ACT == 1) v = tanhf(v);
          else v = v / (1.f + __expf(-v));
          if (OUTF32) ((float*)outp)[(size_t)row * DD + c * 16 + nn] = v;
          else ((unsigned short*)outp)[(size_t)row * DD + c * 16 + nn] = f2bf(v);
        }
      }
    }
  }
}

extern "C" void kernel_launch(void* const* d_in, const int* in_sizes, int n_in,
                              void* d_out, int out_size, void* d_ws, size_t ws_size,
                              hipStream_t stream) {
  const float* h_in = (const float*)d_in[0];
  const int* src    = (const int*)d_in[1];
  const int* dst    = (const int*)d_in[2];
  const float* W1   = (const float*)d_in[3];
  const float* b1   = (const float*)d_in[4];
  const float* W2   = (const float*)d_in[5];
  const float* b2   = (const float*)d_in[6];
  const float* Wself  = (const float*)d_in[7];
  const float* bself  = (const float*)d_in[8];
  const float* Wneigh = (const float*)d_in[9];
  const int N = in_sizes[0] / DD;
  const int E = in_sizes[1];
  float* out = (float*)d_out;

  const int gb = (N + 63) / 64;    // 782 tiles
  const int ab = (N + 3) / 4;      // 12500 aggr blocks
  const int eb = (E + 255) / 256;  // 3125
  const int fb = eb * 8;           // 25000 fill blocks
  const int rstep = (N + 7) / 8;

  char* ws = (char*)d_ws;
  size_t off = 0;
  auto alloc = [&](size_t bytes) -> char* {
    char* p = ws + off;
    off = (off + bytes + 255) & ~(size_t)255;
    return p;
  };
  // ---- zeroed region (single memset) ----
  int* degi  = (int*)alloc((size_t)N * 4);
  int* total = (int*)alloc(256);
  int* flags = (int*)alloc((size_t)3 * gb * 4);  // per-layer tile counters
  size_t zlen = off;
  // ---- uninitialized region ----
  unsigned* wfrag = (unsigned*)alloc(8 * 32768);
  unsigned* actA  = (unsigned*)alloc((size_t)N * 64 * 4);
  unsigned* actB  = (unsigned*)alloc((size_t)N * 64 * 4);
  unsigned* neigh = (unsigned*)alloc((size_t)N * 64 * 4);
  int* esrc     = (int*)alloc((size_t)E * 4);
  int* rowstart = (int*)alloc((size_t)N * 4);
  int* cursor   = (int*)alloc((size_t)N * 4);

  hipMemsetAsync(degi, 0, zlen, stream);
  k_deg_prep<<<eb + 256, 256, 0, stream>>>(dst, degi, E, eb, W1, W2, Wself, Wneigh, wfrag);
  k_alloc<<<(N + 255) / 256, 256, 0, stream>>>(degi, total, rowstart, cursor, N);
  k_fill_fc<<<fb + gb, 256, 0, stream>>>(src, dst, cursor, esrc, E, rstep, fb,
                                         h_in, (const uint4*)wfrag, (const uint4*)wfrag + 2048,
                                         b1, b2, (unsigned short*)actB, N);

  const uint4* wf = (const uint4*)wfrag;
  const unsigned* cur = actB;
  unsigned* nxt = actA;
  for (int l = 0; l < 3; ++l) {
    const uint4* wsF = wf + (size_t)(2 + l) * 2048;
    const uint4* wnF = wf + (size_t)(5 + l) * 2048;
    const float* bs = bself + (size_t)l * DD;
    int* fl = flags + (size_t)l * gb;
    if (l < 2) {
      k_layer_pc<2, false><<<ab + gb, 256, 0, stream>>>((const uint4*)cur, rowstart, degi, esrc,
                                                        (uint4*)neigh, fl, wsF, wnF, bs, nxt, N, ab);
      const unsigned* tmp = cur;
      cur = nxt;
      nxt = (unsigned*)tmp;
    } else {
      k_layer_pc<1, true><<<ab + gb, 256, 0, stream>>>((const uint4*)cur, rowstart, degi, esrc,
                                                       (uint4*)neigh, fl, wsF, wnF, bs, out, N, ab);
    }
  }
}